// Round 9
// baseline (137.328 us; speedup 1.0000x reference)
//
#include <hip/hip_runtime.h>
#include <math.h>

#define NSTEPS 216
#define SEG 27                 // steps per segment (= per thread), all in VGPRs
#define NSEG 8                 // segments (waves) per row
#define ROWS 64                // rows per block (= lanes per wave)
#define THREADS (ROWS * NSEG)  // 512
#define SSTR 116               // staging stride in dwords (= 29 float4, 16B-aligned rows)
#define CHUNK 108              // steps per staging chunk (4 segments, 27 float4/row)
#define QPR 27                 // float4 quads per row per chunk

#if __has_builtin(__builtin_amdgcn_exp2f)
#define EXP2F(x) __builtin_amdgcn_exp2f(x)
#else
#define EXP2F(x) exp2f(x)
#endif

// Fallback table storage if d_ws is unavailable (tbl[0..216)=th, [216..432)=H*z0)
__device__ float g_tbl[2 * NSTEPS];

__global__ void traj_kernel() {   // fallback only
    __shared__ float xs[NSTEPS], ys[NSTEPS];
    const int t = threadIdx.x;
    if (t == 0) {
        float x = (float)(-0.417750770388669);
        float y = (float)(-0.9085616622823985);
        const float W = (float)(2.0 * M_PI);
        const float H = (float)(1.0 / 216.0);
        for (int n = 0; n < NSTEPS; ++n) {
            xs[n] = x; ys[n] = y;
            float alpha = 1.0f - sqrtf(x * x + y * y);
            float fx = alpha * x - W * y;
            float fy = alpha * y + W * x;
            x = x + H * fx;
            y = y + H * fy;
        }
    }
    __syncthreads();
    if (t < NSTEPS) {
        g_tbl[t] = atan2f(ys[t], xs[t]);
        float tf = (float)t / 216.0f;
        g_tbl[NSTEPS + t] = (float)(1.0 / 216.0) * (0.005f * sinf(1.5707964f * tf));
    }
}

// z_n = K*z_{n-1} + c_t is AFFINE in z with z-independent forcing c_t.
// => time-parallel: 8 threads/row each own 27 steps, compute c_t ONCE,
// combine segment affine maps (z -> K^27 z + S), then replay with cheap
// FMAs. R9: write phase fully vectorized — 2 chunks x 108 steps staged at
// stride 116 dwords (29 float4/row), drained with ds_read_b128 +
// global_store_dwordx4 (6.75 units/thread vs 27 scalar r/w); c_lds gone
// (c[27] all-VGPR under (512,4) — no forced 64-reg cliff, the R2 lesson);
// barriers 10 -> 6. z arithmetic bit-identical to R8.
// Lessons kept: R5 v_pk_* asm corrupts (op_sel_hi); R6 in-block table
// fusion wrecks regalloc; R7 wave-per-row adds issue; occupancy is NOT
// the lever (R4 16% == R7 77%) — issue count is.
__global__ __launch_bounds__(THREADS, 4) void euler_kernel(const float* __restrict__ prm,
                                                           const float* __restrict__ v0,
                                                           float* __restrict__ out,
                                                           const float* __restrict__ tbl) {
    __shared__ float th_s[NSTEPS];
    __shared__ float hz0_s[NSTEPS];
    __shared__ float Sz[NSEG][ROWS];      // segment offsets S
    __shared__ float Smn[NSEG][ROWS];     // per-segment min
    __shared__ float Smx[NSEG][ROWS];     // per-segment max
    __shared__ __align__(16) float st_s[ROWS * SSTR];  // 64 rows x 108 staged, stride 116

    const int tid = threadIdx.x;
    const int row = tid & (ROWS - 1);     // lane within wave
    const int seg = tid >> 6;             // wave id = segment id (wave-uniform)

    if (tid < NSTEPS) {
        th_s[tid] = tbl[tid];
        hz0_s[tid] = tbl[NSTEPS + tid];
    }

    const int b = blockIdx.x * ROWS + row;
    const float* p = prm + (size_t)b * 15;

    // gaussian_j(d) = a*d*exp(-d^2/(2b^2)) = d * exp2(d^2*cj2 + la2)
    // with log2e folded into cj2/la2 so the hot loop is pure v_exp_f32.
    const float LOG2E = 1.4426950408889634f;
    float tj[5], cj2[5], la2[5];
#pragma unroll
    for (int j = 0; j < 5; ++j) {
        float a  = p[3 * j + 0];
        float bb = p[3 * j + 1];
        tj[j] = p[3 * j + 2];
        cj2[j] = -LOG2E / (2.0f * bb * bb);
        la2[j] = __log2f(a);
    }

    const float zinit = v0[b];
    const float H = (float)(1.0 / 216.0);
    const float K = 1.0f - H;
    // A = K^27 by squaring (uniform): 16+8+2+1
    const float K2 = K * K, K8 = K2 * K2 * K2 * K2;
    const float A = K8 * K8 * K8 * K2 * K;

    __syncthreads();                      // #1: tables ready

    // ---- heavy pass (ONCE): forcing terms c_t for my 27 steps ----
    const int t0 = seg * SEG;
    float c[SEG];
    float S = 0.0f;                        // segment map applied to z=0
#pragma unroll
    for (int i = 0; i < SEG; ++i) {
        float th = th_s[t0 + i];
        float G = 0.0f;
#pragma unroll
        for (int j = 0; j < 5; ++j) {
            float d = th - tj[j];
            G = fmaf(d, EXP2F(fmaf(d * d, cj2[j], la2[j])), G);
        }
        float ci = fmaf(-H, G, hz0_s[t0 + i]);
        c[i] = ci;
        S = fmaf(S, K, ci);
    }
    Sz[seg][row] = S;
    __syncthreads();                      // #2: Sz ready

    // ---- combine: z at my segment start (seg is wave-uniform -> no div) ----
    float z = zinit;
#pragma unroll
    for (int j = 0; j < NSEG - 1; ++j)
        if (j < seg) z = fmaf(z, A, Sz[j][row]);

    // ---- replay: cheap FMAs, overwrite c[] with z_t, track min/max ----
    float zmn = 3.4e38f, zmx = -3.4e38f;
#pragma unroll
    for (int i = 0; i < SEG; ++i) {
        z = fmaf(z, K, c[i]);
        c[i] = z;
        zmn = fminf(zmn, z);
        zmx = fmaxf(zmx, z);
    }
    Smn[seg][row] = zmn;
    Smx[seg][row] = zmx;
    __syncthreads();                      // #3: min/max tables ready
#pragma unroll
    for (int j = 0; j < NSEG; ++j) {
        zmn = fminf(zmn, Smn[j][row]);
        zmx = fmaxf(zmx, Smx[j][row]);
    }
    const float s = 0.042557f / (zmx - zmn);
    const float o = fmaf(-zmn, s, -0.01563f);

    // ---- staged vectorized write: 2 chunks x 108 steps (4 segments) ----
    const float4* st4 = (const float4*)st_s;
    float4* outQ = (float4*)(out + (size_t)blockIdx.x * (ROWS * NSTEPS));
#pragma unroll
    for (int ch = 0; ch < 2; ++ch) {
        if ((seg >> 2) == ch) {            // wave-uniform: segments 4ch..4ch+3 stage
            const int base = (seg & 3) * SEG;   // local t within chunk
#pragma unroll
            for (int i = 0; i < SEG; ++i)
                st_s[row * SSTR + base + i] = fmaf(c[i], s, o);
        }
        __syncthreads();                   // #4/#6: chunk staged
        // 64 rows x 27 float4 = 1728 units -> 512 threads x 3.375
#pragma unroll
        for (int k = 0; k < 3; ++k) {
            unsigned u = (unsigned)tid + THREADS * k;
            unsigned r = u / QPR;          // compiler magic-div
            unsigned q = u - r * QPR;
            outQ[r * (NSTEPS / 4) + ch * QPR + q] = st4[r * (SSTR / 4) + q];
        }
        if (tid < 1728 - 3 * THREADS) {    // remainder 192
            unsigned u = (unsigned)tid + THREADS * 3;
            unsigned r = u / QPR;
            unsigned q = u - r * QPR;
            outQ[r * (NSTEPS / 4) + ch * QPR + q] = st4[r * (SSTR / 4) + q];
        }
        if (ch == 0) __syncthreads();      // #5: st_s free for chunk 1
    }
}

// ---- host-side table precompute (input-independent constants) ----
static float h_tbl[2 * NSTEPS];
static bool h_tbl_init = false;

static void init_tbl() {
    float xs[NSTEPS], ys[NSTEPS];
    float x = (float)(-0.417750770388669);
    float y = (float)(-0.9085616622823985);
    const float W = (float)(2.0 * M_PI);
    const float Hh = (float)(1.0 / 216.0);
    for (int n = 0; n < NSTEPS; ++n) {
        xs[n] = x; ys[n] = y;
        float alpha = 1.0f - sqrtf(x * x + y * y);
        float fx = alpha * x - W * y;
        float fy = alpha * y + W * x;
        x = x + Hh * fx;
        y = y + Hh * fy;
    }
    for (int t = 0; t < NSTEPS; ++t) {
        h_tbl[t] = atan2f(ys[t], xs[t]);
        float tf = (float)t / 216.0f;
        h_tbl[NSTEPS + t] = (float)(1.0 / 216.0) * (0.005f * sinf(1.5707964f * tf));
    }
}

extern "C" void kernel_launch(void* const* d_in, const int* in_sizes, int n_in,
                              void* d_out, int out_size, void* d_ws, size_t ws_size,
                              hipStream_t stream) {
    const float* x  = (const float*)d_in[0];
    const float* v0 = (const float*)d_in[1];
    float* out = (float*)d_out;
    const int nb = in_sizes[1];              // 131072 batch rows

    if (!h_tbl_init) { init_tbl(); h_tbl_init = true; }

    const float* tbl;
    if (d_ws != nullptr && ws_size >= sizeof(h_tbl)) {
        // 1.7 KB H2D from persistent static buffer: graph-capture-safe async copy.
        hipMemcpyAsync(d_ws, h_tbl, sizeof(h_tbl), hipMemcpyHostToDevice, stream);
        tbl = (const float*)d_ws;
    } else {
        // fallback: device-side table build (adds a dispatch, ~14us)
        static float* s_gtbl = nullptr;
        if (s_gtbl == nullptr)
            hipGetSymbolAddress((void**)&s_gtbl, HIP_SYMBOL(g_tbl));
        hipLaunchKernelGGL(traj_kernel, dim3(1), dim3(256), 0, stream);
        tbl = (const float*)s_gtbl;
    }

    hipLaunchKernelGGL(euler_kernel, dim3(nb / ROWS), dim3(THREADS), 0, stream,
                       x, v0, out, tbl);
}

// Round 10
// 135.466 us; speedup vs baseline: 1.0137x; 1.0137x over previous
//
#include <hip/hip_runtime.h>
#include <math.h>

#define NSTEPS 216
#define SEG 27                 // steps per segment (= per thread)
#define CREG 18                // c[0..CREG) in VGPRs, rest in LDS
#define NSEG 8                 // segments (waves) per row
#define ROWS 64                // rows per block (= lanes per wave)
#define THREADS (ROWS * NSEG)  // 512
#define CSTR 55                // LDS staging stride, coprime with 32 banks

#if __has_builtin(__builtin_amdgcn_exp2f)
#define EXP2F(x) __builtin_amdgcn_exp2f(x)
#else
#define EXP2F(x) exp2f(x)
#endif

typedef float f2 __attribute__((ext_vector_type(2)));

// Fallback table storage if d_ws is unavailable (tbl[0..216)=th, [216..432)=H*z0)
__device__ float g_tbl[2 * NSTEPS];

__global__ void traj_kernel() {   // fallback only
    __shared__ float xs[NSTEPS], ys[NSTEPS];
    const int t = threadIdx.x;
    if (t == 0) {
        float x = (float)(-0.417750770388669);
        float y = (float)(-0.9085616622823985);
        const float W = (float)(2.0 * M_PI);
        const float H = (float)(1.0 / 216.0);
        for (int n = 0; n < NSTEPS; ++n) {
            xs[n] = x; ys[n] = y;
            float alpha = 1.0f - sqrtf(x * x + y * y);
            float fx = alpha * x - W * y;
            float fy = alpha * y + W * x;
            x = x + H * fx;
            y = y + H * fy;
        }
    }
    __syncthreads();
    if (t < NSTEPS) {
        g_tbl[t] = atan2f(ys[t], xs[t]);
        float tf = (float)t / 216.0f;
        g_tbl[NSTEPS + t] = (float)(1.0 / 216.0) * (0.005f * sinf(1.5707964f * tf));
    }
}

// z_n = K*z_{n-1} + c_t is AFFINE in z with z-independent forcing c_t.
// => time-parallel: 8 threads/row each own 27 steps, compute c_t ONCE,
// combine segment affine maps (z -> K^27 z + S), then replay with cheap
// FMAs. c[] split 18-in-VGPR + 9-in-LDS to satisfy (512,8) spill-free.
// R10 = R8 (best, 134.8us) + packed-f32 G-loop via COMPILER-generated
// v_pk_* from float2 ext_vector arithmetic (R5 lesson: never hand-asm
// VOP3P — op_sel_hi defaults corrupt; C-level float2 is the safe path).
// R9 lesson: write-phase vectorization was neutral-negative — reverted.
// Occupancy is NOT the lever (R4 16% == R7 77%); issue count is.
__global__ __launch_bounds__(THREADS, 8) void euler_kernel(const float* __restrict__ prm,
                                                           const float* __restrict__ v0,
                                                           float* __restrict__ out,
                                                           const float* __restrict__ tbl) {
    __shared__ float th_s[NSTEPS];
    __shared__ float hz0_s[NSTEPS];
    __shared__ float Sz[NSEG][ROWS];      // segment offsets S
    __shared__ float Smn[NSEG][ROWS];     // per-segment min
    __shared__ float Smx[NSEG][ROWS];     // per-segment max
    __shared__ float st_s[ROWS * CSTR];   // 64 rows x 54 scaled outputs, stride 55
    __shared__ float c_lds[SEG - CREG][THREADS];  // 9 x 512, lane-stride: conflict-free

    const int tid = threadIdx.x;
    const int row = tid & (ROWS - 1);     // lane within wave
    const int seg = tid >> 6;             // wave id = segment id (wave-uniform)

    if (tid < NSTEPS) {
        th_s[tid] = tbl[tid];
        hz0_s[tid] = tbl[NSTEPS + tid];
    }

    const int b = blockIdx.x * ROWS + row;
    const float* p = prm + (size_t)b * 15;

    // gaussian_j(d) = a*d*exp(-d^2/(2b^2)) = d * exp2(d^2*cj2 + la2)
    // with log2e folded into cj2/la2 so the hot loop is pure v_exp_f32.
    // Gaussians {0,1},{2,3} packed as float2 (compiler emits v_pk_*); j=4 scalar.
    const float LOG2E = 1.4426950408889634f;
    f2 tj01, tj23, cj01, cj23, la01, la23;
    float tj4, cj4, la4;
    {
        float tj[5], cj2[5], la2[5];
#pragma unroll
        for (int j = 0; j < 5; ++j) {
            float a  = p[3 * j + 0];
            float bb = p[3 * j + 1];
            tj[j] = p[3 * j + 2];
            cj2[j] = -LOG2E / (2.0f * bb * bb);
            la2[j] = __log2f(a);
        }
        tj01 = (f2){tj[0], tj[1]};  tj23 = (f2){tj[2], tj[3]};  tj4 = tj[4];
        cj01 = (f2){cj2[0], cj2[1]}; cj23 = (f2){cj2[2], cj2[3]}; cj4 = cj2[4];
        la01 = (f2){la2[0], la2[1]}; la23 = (f2){la2[2], la2[3]}; la4 = la2[4];
    }

    const float zinit = v0[b];
    const float H = (float)(1.0 / 216.0);
    const float K = 1.0f - H;
    // A = K^27 by squaring (uniform): 16+8+2+1
    const float K2 = K * K, K8 = K2 * K2 * K2 * K2;
    const float A = K8 * K8 * K8 * K2 * K;

    __syncthreads();

    // ---- heavy pass (ONCE): forcing terms c_t for my 27 steps ----
    const int t0 = seg * SEG;
    float c[CREG];
    float S = 0.0f;                        // segment map applied to z=0
#pragma unroll
    for (int i = 0; i < SEG; ++i) {
        float th = th_s[t0 + i];
        f2 thv = (f2){th, th};
        f2 d01 = thv - tj01;               // v_pk_add
        f2 d23 = thv - tj23;
        float d4 = th - tj4;
        f2 x01 = __builtin_elementwise_fma(d01 * d01, cj01, la01);  // pk_mul + pk_fma
        f2 x23 = __builtin_elementwise_fma(d23 * d23, cj23, la23);
        float x4 = fmaf(d4 * d4, cj4, la4);
        f2 e01 = (f2){EXP2F(x01.x), EXP2F(x01.y)};   // scalar trans (no packed exp)
        f2 e23 = (f2){EXP2F(x23.x), EXP2F(x23.y)};
        float e4 = EXP2F(x4);
        f2 ge = __builtin_elementwise_fma(d23, e23, d01 * e01);     // pk_mul + pk_fma
        float G = fmaf(d4, e4, ge.x + ge.y);
        float ci = fmaf(-H, G, hz0_s[t0 + i]);
        if (i < CREG) c[i] = ci;           // compile-time split (full unroll)
        else          c_lds[i - CREG][tid] = ci;
        S = fmaf(S, K, ci);
    }
    Sz[seg][row] = S;
    __syncthreads();

    // ---- combine: z at my segment start (seg is wave-uniform -> no div) ----
    float z = zinit;
#pragma unroll
    for (int j = 0; j < NSEG - 1; ++j)
        if (j < seg) z = fmaf(z, A, Sz[j][row]);

    // ---- replay: cheap FMAs, overwrite storage with z_t, track min/max ----
    float zmn = 3.4e38f, zmx = -3.4e38f;
#pragma unroll
    for (int i = 0; i < SEG; ++i) {
        float ci = (i < CREG) ? c[i] : c_lds[i - CREG][tid];
        z = fmaf(z, K, ci);
        if (i < CREG) c[i] = z;
        else          c_lds[i - CREG][tid] = z;
        zmn = fminf(zmn, z);
        zmx = fmaxf(zmx, z);
    }
    Smn[seg][row] = zmn;
    Smx[seg][row] = zmx;
    __syncthreads();
#pragma unroll
    for (int j = 0; j < NSEG; ++j) {
        zmn = fminf(zmn, Smn[j][row]);
        zmx = fmaxf(zmx, Smx[j][row]);
    }
    const float s = 0.042557f / (zmx - zmn);
    const float o = fmaf(-zmn, s, -0.01563f);

    // ---- staged coalesced write: chunk = 2 segments = 54 steps ----
    float* outB = out + (size_t)blockIdx.x * (ROWS * NSTEPS);
#pragma unroll
    for (int ch = 0; ch < NSEG / 2; ++ch) {
        if ((seg >> 1) == ch) {            // wave-uniform
            const int base = (seg & 1) * SEG;
#pragma unroll
            for (int i = 0; i < SEG; ++i) {
                float zi = (i < CREG) ? c[i] : c_lds[i - CREG][tid];
                st_s[row * CSTR + base + i] = fmaf(zi, s, o);
            }
        }
        __syncthreads();
        // 64*54 = 3456 staged elements -> 512 threads x 6.75
#pragma unroll
        for (int k = 0; k < 6; ++k) {
            unsigned idx = (unsigned)tid + THREADS * k;
            unsigned r = idx / 54u;
            unsigned tt = idx - r * 54u;
            outB[r * NSTEPS + ch * 54 + tt] = st_s[r * CSTR + tt];
        }
        if (tid < 3456 - 6 * THREADS) {
            unsigned idx = (unsigned)tid + THREADS * 6;
            unsigned r = idx / 54u;
            unsigned tt = idx - r * 54u;
            outB[r * NSTEPS + ch * 54 + tt] = st_s[r * CSTR + tt];
        }
        __syncthreads();
    }
}

// ---- host-side table precompute (input-independent constants) ----
static float h_tbl[2 * NSTEPS];
static bool h_tbl_init = false;

static void init_tbl() {
    float xs[NSTEPS], ys[NSTEPS];
    float x = (float)(-0.417750770388669);
    float y = (float)(-0.9085616622823985);
    const float W = (float)(2.0 * M_PI);
    const float Hh = (float)(1.0 / 216.0);
    for (int n = 0; n < NSTEPS; ++n) {
        xs[n] = x; ys[n] = y;
        float alpha = 1.0f - sqrtf(x * x + y * y);
        float fx = alpha * x - W * y;
        float fy = alpha * y + W * x;
        x = x + Hh * fx;
        y = y + Hh * fy;
    }
    for (int t = 0; t < NSTEPS; ++t) {
        h_tbl[t] = atan2f(ys[t], xs[t]);
        float tf = (float)t / 216.0f;
        h_tbl[NSTEPS + t] = (float)(1.0 / 216.0) * (0.005f * sinf(1.5707964f * tf));
    }
}

extern "C" void kernel_launch(void* const* d_in, const int* in_sizes, int n_in,
                              void* d_out, int out_size, void* d_ws, size_t ws_size,
                              hipStream_t stream) {
    const float* x  = (const float*)d_in[0];
    const float* v0 = (const float*)d_in[1];
    float* out = (float*)d_out;
    const int nb = in_sizes[1];              // 131072 batch rows

    if (!h_tbl_init) { init_tbl(); h_tbl_init = true; }

    const float* tbl;
    if (d_ws != nullptr && ws_size >= sizeof(h_tbl)) {
        // 1.7 KB H2D from persistent static buffer: graph-capture-safe async copy.
        hipMemcpyAsync(d_ws, h_tbl, sizeof(h_tbl), hipMemcpyHostToDevice, stream);
        tbl = (const float*)d_ws;
    } else {
        // fallback: device-side table build (adds a dispatch, ~14us)
        static float* s_gtbl = nullptr;
        if (s_gtbl == nullptr)
            hipGetSymbolAddress((void**)&s_gtbl, HIP_SYMBOL(g_tbl));
        hipLaunchKernelGGL(traj_kernel, dim3(1), dim3(256), 0, stream);
        tbl = (const float*)s_gtbl;
    }

    hipLaunchKernelGGL(euler_kernel, dim3(nb / ROWS), dim3(THREADS), 0, stream,
                       x, v0, out, tbl);
}